// Round 12
// baseline (932.264 us; speedup 1.0000x reference)
//
#include <hip/hip_runtime.h>
#include <math.h>

#define NPIX  25600      // 160*160
#define NANCH 76800      // 3*NPIX

// output layout (float elements)
constexpr int OUT_ANCH = 0;        // 76800*4
constexpr int OUT_OBJ  = 307200;   // 76800
constexpr int OUT_DELT = 384000;   // 76800*4
constexpr int OUT_FL   = 691200;   // 1000
constexpr int OUT_FB   = 692200;   // 1000*4

// workspace layout (bytes)
constexpr size_t Y_OFF      = 0;                        // 26,214,400 (f32)
constexpr size_t PROPS_OFF  = 26214400;                 // 76800*4*8 = 2,457,600
constexpr size_t KEYF_OFF   = PROPS_OFF + 2457600;      // 76800*4
constexpr size_t CANDK_OFF  = KEYF_OFF + 307200;        // 4096*4
constexpr size_t CANDI_OFF  = CANDK_OFF + 16384;        // 4096*4
constexpr size_t TSC_OFF    = CANDI_OFF + 16384;        // 2000*4 -> 8192
constexpr size_t TBOX_OFF   = TSC_OFF + 8192;           // 2000*4*8 -> 65536
constexpr size_t HIST_OFF   = TBOX_OFF + 65536;         // 256*4 -> 1024 (dead in V12)
constexpr size_t STATE_OFF  = HIST_OFF + 1024;          // -> 256
constexpr size_t MASK32_OFF = STATE_OFF + 256;          // 2000*64*4 = 512000
// Transient overlays (all stream-order safe):
//   wt  [ci][oc][9] (2.36 MB) at PROPS_OFF   : conv-time only; heads writes props after.
//   wt2 [c][16]     (16 KB)   at MASK32_OFF  : heads-time only; iou_mask writes later.
//   h16 [65536]     (256 KB)  at MASK32_OFF+16384 : select-time only (zeroed by heads,
//                                filled by hist16, read by pick16); iou_mask writes later.

struct SelState { unsigned prefix; int remaining; int cntHi; int cntEq; };

__device__ __forceinline__ unsigned orderKey32(float f) {
  unsigned u = __float_as_uint(f);
  return (u & 0x80000000u) ? ~u : (u | 0x80000000u);
}
__device__ __forceinline__ float key32ToFloat(unsigned k) {
  unsigned u = (k & 0x80000000u) ? (k & 0x7fffffffu) : ~k;
  return __uint_as_float(u);
}

// ---------------------------------------------------------------- prep_all: init + weight transposes (merged, 1 launch)
// wt[ci][oc][9]  <- conv_w[oc][ci][9]   (72 contiguous floats/ci/wave for conv)
// wt2[c][16]     <- {det_w[0..2][c], reg_w[0..11][c], pad}  (one s_load_dwordx16/c for heads)
__global__ __launch_bounds__(256) void prep_all(const float* __restrict__ w,
                                                float* __restrict__ wt,
                                                const float* __restrict__ det_w,
                                                const float* __restrict__ reg_w,
                                                float* __restrict__ wt2,
                                                float* __restrict__ out,
                                                SelState* __restrict__ st) {
  int gid = blockIdx.x * 256 + threadIdx.x;   // 2304*256 = 589824 exactly
  int oc  = gid / 2304;
  int rem = gid - oc * 2304;
  int ci  = rem / 9;
  int t   = rem - ci * 9;
  wt[((size_t)ci * 256 + oc) * 9 + t] = w[gid];
  if (gid < 4096) {
    int c = gid >> 4, j = gid & 15;
    float v = 0.f;
    if (j < 3) v = det_w[j * 256 + c];
    else if (j < 15) v = reg_w[(j - 3) * 256 + c];
    wt2[gid] = v;
  }
  if (gid < 1000) out[OUT_FL + gid] = -1e9f;
  if (gid < 4000) out[OUT_FB + gid] = 0.f;
  if (gid == 0) { st->prefix = 0u; st->remaining = 2000; st->cntHi = 0; st->cntEq = 0; }
}

// ---------------------------------------------------------------- hybrid conv + bn + relu
// NUMERICS FROZEN (R9/R10/R11 pass): per-output fmaf chain ic 255->0, taps 8->0.
// V5 (proven 566us conv / 930us total): inputs via zero-padded LDS tile;
// weights via SCALAR pipe from transposed wt (L2-resident). V6-V9 all
// regressed (load sinking / wave-ci overhead / SGPR serialization / addressing
// growth) -- this codegen is a verified local optimum; DO NOT perturb.
__global__ __launch_bounds__(256) void conv_hyb_f32r(
    const float* __restrict__ x, const float* __restrict__ wt,
    const float* __restrict__ bv, const float* __restrict__ gamma,
    const float* __restrict__ beta, const float* __restrict__ mean,
    const float* __restrict__ var, float* __restrict__ y) {
  const int tile = blockIdx.x;                 // 100 tiles: 10x10 of 16x16 px
  const int th0 = (tile / 10) * 16;
  const int tw0 = (tile - (tile / 10) * 10) * 16;
  const int ob  = blockIdx.y * 32;             // 32 oc per block
  const int tid = threadIdx.x;
  const int wid  = __builtin_amdgcn_readfirstlane(tid >> 6);   // wave -> 8 oc
  const int lane = tid & 63;
  const int r  = lane >> 2;                    // output row (0..15)
  const int cg = lane & 3;                     // col group (4 px)
  const int oc0 = ob + wid * 8;

  __shared__ __align__(16) float lin[8][18][20];   // 2880 floats; halo 18x18, stride 20

  float sreg[11];                              // 11*256 = 2816 >= 2592 staged elems
  auto loadRegs = [&](int cb) {
#pragma unroll
    for (int k = 0; k < 11; ++k) {
      int idx = tid + k * 256;
      float v = 0.f;
      if (idx < 2592) {
        int ci = idx / 324; int rem = idx - ci * 324;
        int rr = rem / 18;  int cc = rem - rr * 18;
        int gh = th0 + rr - 1, gw = tw0 + cc - 1;
        if ((unsigned)gh < 160u && (unsigned)gw < 160u)
          v = x[(size_t)(cb + ci) * NPIX + gh * 160 + gw];
      }
      sreg[k] = v;
    }
  };
  auto writeRegs = [&]() {
#pragma unroll
    for (int k = 0; k < 11; ++k) {
      int idx = tid + k * 256;
      if (idx < 2592) {
        int ci = idx / 324; int rem = idx - ci * 324;
        int rr = rem / 18;  int cc = rem - rr * 18;
        lin[ci][rr][cc] = sreg[k];
      }
    }
  };

  float acc[8][4];
#pragma unroll
  for (int o = 0; o < 8; ++o)
#pragma unroll
    for (int j = 0; j < 4; ++j) acc[o][j] = 0.f;

  loadRegs(248);
  for (int cb = 248; cb >= 0; cb -= 8) {       // ic blocks DESCENDING
    __syncthreads();
    writeRegs();
    __syncthreads();
    if (cb > 0) loadRegs(cb - 8);              // prefetch next chunk
#pragma unroll
    for (int ci = 7; ci >= 0; --ci) {          // ic DESCENDING within block
      float in0[6], in1[6], in2[6];
      const float* base = &lin[ci][r][cg * 4];     // 16B aligned
      {
        float4 q = *(const float4*)(base);
        float2 p = *(const float2*)(base + 4);
        in0[0] = q.x; in0[1] = q.y; in0[2] = q.z; in0[3] = q.w; in0[4] = p.x; in0[5] = p.y;
      }
      {
        float4 q = *(const float4*)(base + 20);
        float2 p = *(const float2*)(base + 24);
        in1[0] = q.x; in1[1] = q.y; in1[2] = q.z; in1[3] = q.w; in1[4] = p.x; in1[5] = p.y;
      }
      {
        float4 q = *(const float4*)(base + 40);
        float2 p = *(const float2*)(base + 44);
        in2[0] = q.x; in2[1] = q.y; in2[2] = q.z; in2[3] = q.w; in2[4] = p.x; in2[5] = p.y;
      }
      // 72 contiguous floats, wave-uniform address -> wide s_loads (L2-resident)
      const float* wb = wt + ((size_t)(cb + ci) * 256 + oc0) * 9;
#pragma unroll
      for (int o = 0; o < 8; ++o) {
        const float w0 = wb[o * 9 + 0], w1 = wb[o * 9 + 1], w2 = wb[o * 9 + 2];
        const float w3 = wb[o * 9 + 3], w4 = wb[o * 9 + 4], w5 = wb[o * 9 + 5];
        const float w6 = wb[o * 9 + 6], w7 = wb[o * 9 + 7], w8 = wb[o * 9 + 8];
#pragma unroll
        for (int j = 0; j < 4; ++j) {
          // frozen chain: taps 8->0
          float a = acc[o][j];
          a = fmaf(in2[j + 2], w8, a); a = fmaf(in2[j + 1], w7, a); a = fmaf(in2[j + 0], w6, a);
          a = fmaf(in1[j + 2], w5, a); a = fmaf(in1[j + 1], w4, a); a = fmaf(in1[j + 0], w3, a);
          a = fmaf(in0[j + 2], w2, a); a = fmaf(in0[j + 1], w1, a); a = fmaf(in0[j + 0], w0, a);
          acc[o][j] = a;
        }
      }
    }
  }

  const int gh = th0 + r, gw0 = tw0 + cg * 4;
#pragma unroll
  for (int o = 0; o < 8; ++o) {
    int oc = oc0 + o;
    float sc = gamma[oc] / sqrtf(var[oc] + 1e-5f);
    float sh = (bv[oc] - mean[oc]) * sc + beta[oc];
    float4 vv;
    float v0 = fmaf(acc[o][0], sc, sh); vv.x = (v0 > 0.f) ? v0 : 0.f;
    float v1 = fmaf(acc[o][1], sc, sh); vv.y = (v1 > 0.f) ? v1 : 0.f;
    float v2 = fmaf(acc[o][2], sc, sh); vv.z = (v2 > 0.f) ? v2 : 0.f;
    float v3 = fmaf(acc[o][3], sc, sh); vv.w = (v3 > 0.f) ? v3 : 0.f;
    *(float4*)&y[(size_t)oc * NPIX + gh * 160 + gw0] = vv;   // gw0 mult of 4 -> aligned
  }
}

// ---------------------------------------------------------------- heads (f32, reversed c) + anchors + proposals
// NUMERICS FROZEN: identical fmaf chain (c 255->0) with identical weight
// VALUES via packed wt2[c][16] -> one s_load_dwordx16 per c. Also zeroes h16
// for the upcoming hist16 pass (region dead here; 3 stores/thread).
__global__ __launch_bounds__(64) void heads_kernel(
    const float* __restrict__ y, const float* __restrict__ wt2,
    const float* __restrict__ det_b, const float* __restrict__ reg_b,
    float* __restrict__ out, double* __restrict__ props,
    float* __restrict__ keyf, unsigned* __restrict__ h16) {
  const int p = blockIdx.x * 64 + threadIdx.x;
  h16[p] = 0u; h16[p + 25600] = 0u;
  if (p + 51200 < 65536) h16[p + 51200] = 0u;
  float od0 = 0.f, od1 = 0.f, od2 = 0.f;
  float rg[12];
#pragma unroll
  for (int o = 0; o < 12; ++o) rg[o] = 0.f;
  const float* yp = y + p;
  for (int c = 255; c >= 0; --c) {      // reversed accumulation
    float v = yp[(size_t)c * NPIX];
    const float* wc = wt2 + c * 16;     // wave-uniform, 64B-aligned -> s_load_dwordx16
    od0 = fmaf(v, wc[0], od0);
    od1 = fmaf(v, wc[1], od1);
    od2 = fmaf(v, wc[2], od2);
#pragma unroll
    for (int o = 0; o < 12; ++o) rg[o] = fmaf(v, wc[3 + o], rg[o]);
  }
  const int hh = p / 160;
  const int ww = p - hh * 160;
  const float sx = ww * 4.0f, sy = hh * 4.0f;
  float odv[3] = {od0, od1, od2};
#pragma unroll
  for (int a = 0; a < 3; ++a) {
    float ar = (a == 0) ? 0.5f : ((a == 1) ? 1.0f : 2.0f);
    float sq = sqrtf(ar);
    float haf = 64.0f * sq, waf = 64.0f / sq;
    float ax1 = fminf(fmaxf(sx - waf * 0.5f, 0.f), 640.f);
    float ay1 = fminf(fmaxf(sy - haf * 0.5f, 0.f), 640.f);
    float ax2 = fminf(fmaxf(sx + waf * 0.5f, 0.f), 640.f);
    float ay2 = fminf(fmaxf(sy + haf * 0.5f, 0.f), 640.f);
    int ai = a * NPIX + p;
    out[OUT_ANCH + ai * 4 + 0] = ax1;
    out[OUT_ANCH + ai * 4 + 1] = ay1;
    out[OUT_ANCH + ai * 4 + 2] = ax2;
    out[OUT_ANCH + ai * 4 + 3] = ay2;
    float logit = odv[a] + det_b[a];
    out[OUT_OBJ + ai] = logit;
    float dx = rg[0 + a] + reg_b[0 + a];
    float dy = rg[3 + a] + reg_b[3 + a];
    float dw = rg[6 + a] + reg_b[6 + a];
    float dh = rg[9 + a] + reg_b[9 + a];
    out[OUT_DELT + ai * 4 + 0] = dx;
    out[OUT_DELT + ai * 4 + 1] = dy;
    out[OUT_DELT + ai * 4 + 2] = dw;
    out[OUT_DELT + ai * 4 + 3] = dh;
    float aw = ax2 - ax1, ah = ay2 - ay1;
    float cx = ax1 + 0.5f * aw, cy = ay1 + 0.5f * ah;
    float pcx = dx * aw + cx, pcy = dy * ah + cy;
    float pw = aw * expf(dw), ph = ah * expf(dh);
    props[ai * 4 + 0] = (double)fminf(fmaxf(pcx - 0.5f * pw, 0.f), 640.f);
    props[ai * 4 + 1] = (double)fminf(fmaxf(pcy - 0.5f * ph, 0.f), 640.f);
    props[ai * 4 + 2] = (double)fminf(fmaxf(pcx + 0.5f * pw, 0.f), 640.f);
    props[ai * 4 + 3] = (double)fminf(fmaxf(pcy + 0.5f * ph, 0.f), 640.f);
    keyf[ai] = (logit > 0.f) ? logit : -1e9f;   // sigmoid>0.5 <=> logit>0
  }
}

// ---------------------------------------------------------------- 16-bit-bucket select (replaces 4-pass radix: 9 launches -> 3)
// Semantics PROVABLY identical to the 4-pass version: candidates = {hi16 > B}
// (< 2000 items) U {hi16 == B} superset of exact top-2000; bitonic
// (key desc, idx asc) then picks the same 2000 (stable-top_k tie order).
// Sentinel keys (-1e9, ~38K) are skipped: their bucket (0x3191) is provably
// below B (positive-logit buckets are >= 0x8000, and positives >> 2000),
// so skipping kills the same-address atomic hotspot without changing S(b)
// for any queried b.
__global__ __launch_bounds__(256) void hist16_kernel(const float* __restrict__ keyf,
                                                     unsigned* __restrict__ h16) {
  int i = blockIdx.x * 256 + threadIdx.x;   // 300*256 = 76800 exactly
  float kf = keyf[i];
  if (kf > -5e8f) atomicAdd(&h16[orderKey32(kf) >> 16], 1u);
}

__global__ __launch_bounds__(256) void pick16_kernel(const unsigned* __restrict__ h16,
                                                     SelState* __restrict__ st) {
  __shared__ unsigned suf[256];
  const int t = threadIdx.x;
  const uint4* hp = (const uint4*)(h16 + t * 256);
  unsigned csum = 0;
#pragma unroll
  for (int q = 0; q < 64; ++q) { uint4 v = hp[q]; csum += v.x + v.y + v.z + v.w; }
  suf[t] = csum;
  __syncthreads();
  if (t == 0) {                       // serial suffix-scan over 256 chunk sums
    unsigned run = 0;
    for (int i = 255; i >= 0; --i) { run += suf[i]; suf[i] = run; }
  }
  __syncthreads();
  unsigned mine  = suf[t];
  unsigned above = (t == 255) ? 0u : suf[t + 1];
  if (mine >= 2000u && above < 2000u) {     // unique winner chunk
    unsigned run = above; int B = t * 256;
    for (int b = 255; b >= 0; --b) {
      run += h16[t * 256 + b];
      if (run >= 2000u) { B = t * 256 + b; break; }
    }
    st->prefix = (unsigned)B;               // B = max b with S(b) >= 2000
    st->cntHi = 0; st->cntEq = 0;
  }
  if (t == 0 && suf[0] < 2000u) {           // degenerate fallback (never for this data)
    st->prefix = orderKey32(-1e9f) >> 16;
    st->cntHi = 0; st->cntEq = 0;
  }
}

__global__ __launch_bounds__(256) void compact_kernel(const float* __restrict__ keyf,
                                                      SelState* __restrict__ st,
                                                      unsigned* __restrict__ candk,
                                                      unsigned* __restrict__ candi) {
  int i = blockIdx.x * 256 + threadIdx.x;
  if (i >= NANCH) return;
  unsigned k = orderKey32(keyf[i]);
  unsigned B = st->prefix;
  unsigned h = k >> 16;
  if (h > B) {
    int pos = atomicAdd(&st->cntHi, 1);
    if (pos < 2048) { candk[pos] = k; candi[pos] = (unsigned)i; }
  } else if (h == B) {
    int pos = atomicAdd(&st->cntEq, 1);
    if (pos < 2048) { candk[2048 + pos] = k; candi[2048 + pos] = (unsigned)i; }
  }
}

__global__ __launch_bounds__(1024) void sort_gather(const unsigned* __restrict__ candk,
                                                    const unsigned* __restrict__ candi,
                                                    const SelState* __restrict__ st,
                                                    const double* __restrict__ props,
                                                    float* __restrict__ tsc,
                                                    double* __restrict__ tbox) {
  __shared__ unsigned ka[4096];
  __shared__ unsigned ia[4096];
  int nHi = st->cntHi; if (nHi > 2048) nHi = 2048;
  int nEq = st->cntEq; if (nEq > 2048) nEq = 2048;
  for (int i = threadIdx.x; i < 4096; i += 1024) {
    bool real = (i < nHi) || (i >= 2048 && i < 2048 + nEq);
    ka[i] = real ? candk[i] : 0u;
    ia[i] = real ? candi[i] : 0xffffffffu;
  }
  __syncthreads();
  for (int k = 2; k <= 4096; k <<= 1) {
    for (int j = k >> 1; j > 0; j >>= 1) {
      for (int e = threadIdx.x; e < 4096; e += 1024) {
        int l = e ^ j;
        if (l > e) {
          unsigned ke = ka[e], kl = ka[l];
          unsigned ie = ia[e], il = ia[l];
          bool descending = ((e & k) == 0);
          bool lBetter = (kl > ke) || (kl == ke && il < ie);
          bool eBetter = (ke > kl) || (ke == kl && ie < il);
          bool sw = descending ? lBetter : eBetter;
          if (sw) { ka[e] = kl; ka[l] = ke; ia[e] = il; ia[l] = ie; }
        }
      }
      __syncthreads();
    }
  }
  for (int t = threadIdx.x; t < 2000; t += 1024) {
    unsigned idx = ia[t];
    if (idx < (unsigned)NANCH) {
      tsc[t] = key32ToFloat(ka[t]);
      tbox[t * 4 + 0] = props[(size_t)idx * 4 + 0];
      tbox[t * 4 + 1] = props[(size_t)idx * 4 + 1];
      tbox[t * 4 + 2] = props[(size_t)idx * 4 + 2];
      tbox[t * 4 + 3] = props[(size_t)idx * 4 + 3];
    } else {
      tsc[t] = -1e9f;     // invalid: never kept, never output
      tbox[t * 4 + 0] = 0.0; tbox[t * 4 + 1] = 0.0;
      tbox[t * 4 + 2] = 0.0; tbox[t * 4 + 3] = 0.0;
    }
  }
}

// ---------------------------------------------------------------- IoU bitmask (parallel; f64 formula verbatim from R11 NMS)
// word layout: mask32[i*64 + l] covers j in [l*32, l*32+32); bits only for j>i.
__global__ __launch_bounds__(256) void iou_mask(const double* __restrict__ tbox,
                                                unsigned* __restrict__ mask32) {
  int gid = blockIdx.x * 256 + threadIdx.x;
  if (gid >= 2000 * 64) return;
  int i = gid >> 6, l = gid & 63;
  int j0 = l * 32;
  unsigned m = 0u;
  if (j0 + 31 > i) {                       // word contains some j>i
    double bix = tbox[i * 4 + 0], biy = tbox[i * 4 + 1];
    double biz = tbox[i * 4 + 2], biw = tbox[i * 4 + 3];
    double areai = (biz - bix) * (biw - biy);
#pragma unroll 4
    for (int b = 0; b < 32; ++b) {
      int j = j0 + b;
      if (j >= 2000 || j <= i) continue;
      double bjx = tbox[j * 4 + 0], bjy = tbox[j * 4 + 1];
      double bjz = tbox[j * 4 + 2], bjw = tbox[j * 4 + 3];
      double xx1 = fmax(bix, bjx), yy1 = fmax(biy, bjy);
      double xx2 = fmin(biz, bjz), yy2 = fmin(biw, bjw);
      double iw = fmax(xx2 - xx1, 0.0), ih = fmax(yy2 - yy1, 0.0);
      double inter = iw * ih;
      double areaj = (bjz - bjx) * (bjw - bjy);
      double iou = inter / (areai + areaj - inter + 1e-9);
      if (iou > 0.7) m |= (1u << b);
    }
  }
  mask32[(size_t)i * 64 + l] = m;
}

// ---------------------------------------------------------------- greedy scan V5 (proven): register-resident, word-granular
__global__ __launch_bounds__(64) void nms_scan(const unsigned* __restrict__ mask32,
                                               const float* __restrict__ tsc,
                                               const double* __restrict__ tbox,
                                               float* __restrict__ out) {
  __shared__ unsigned kw[64];
  __shared__ unsigned wpfx[65];
  __shared__ __align__(16) unsigned stage[2][2048];   // 2 x 8KB mask-row slabs
  const int lane = threadIdx.x;

  // valid bits (single wave: LDS ops complete in program order)
  kw[lane] = 0u;
  for (int i = lane; i < 2000; i += 64)
    if (tsc[i] > -5e8f) atomicOr(&kw[i >> 5], 1u << (i & 31));
  const unsigned Vw = kw[lane];      // lane's valid word
  unsigned S = 0u;                   // lane's suppression word (grows monotonically)

  // staging: word w's 32 rows are a CONTIGUOUS 8KB slab mask32[w*2048 .. +2048)
  uint4 s0, s1, s2, s3, s4, s5, s6, s7;
  int nchunks = 0;
  auto stageLoad = [&](int w) {
    int rows = 2000 - w * 32; if (rows > 32) rows = 32;
    nchunks = rows >> 2;                       // 8 full words, 4 for word 62
    const uint4* src = (const uint4*)(mask32 + (size_t)w * 2048);
    if (nchunks > 0) s0 = src[0 * 64 + lane];
    if (nchunks > 1) s1 = src[1 * 64 + lane];
    if (nchunks > 2) s2 = src[2 * 64 + lane];
    if (nchunks > 3) s3 = src[3 * 64 + lane];
    if (nchunks > 4) s4 = src[4 * 64 + lane];
    if (nchunks > 5) s5 = src[5 * 64 + lane];
    if (nchunks > 6) s6 = src[6 * 64 + lane];
    if (nchunks > 7) s7 = src[7 * 64 + lane];
  };
  auto stageWrite = [&](int buf) {
    uint4* dst = (uint4*)&stage[buf][0];
    if (nchunks > 0) dst[0 * 64 + lane] = s0;
    if (nchunks > 1) dst[1 * 64 + lane] = s1;
    if (nchunks > 2) dst[2 * 64 + lane] = s2;
    if (nchunks > 3) dst[3 * 64 + lane] = s3;
    if (nchunks > 4) dst[4 * 64 + lane] = s4;
    if (nchunks > 5) dst[5 * 64 + lane] = s5;
    if (nchunks > 6) dst[6 * 64 + lane] = s6;
    if (nchunks > 7) dst[7 * 64 + lane] = s7;
  };

  stageLoad(0);
  stageWrite(0);                                // word 0 ready (one unavoidable stall)
  for (int w = 0; w < 63; ++w) {                // 63 words cover 2000 candidates
    const int buf = w & 1;
    if (w + 1 < 63) stageLoad(w + 1);           // issue next slab's loads (vmcnt)
    // process word w from stage[buf] (LDS reads hide the in-flight global loads)
    unsigned rem = (unsigned)__shfl((int)(Vw & ~S), w);
    while (rem) {
      int b = __ffs(rem) - 1;                   // lowest set bit = next kept i
      rem &= rem - 1;
      unsigned mlane = stage[buf][b * 64 + lane];   // per-lane mask word of row i
      unsigned supw  = stage[buf][b * 64 + w];      // broadcast: row i's word w
      S |= mlane;                               // suppress in future words
      rem &= ~supw;                             // suppress within current word (bits j>i only)
    }
    if (w + 1 < 63) stageWrite(buf ^ 1);        // write next slab (loads mostly landed)
  }
  kw[lane] = Vw & ~S;                           // final keep words

  if (lane == 0) {
    wpfx[0] = 0;
    for (int w = 0; w < 64; ++w) wpfx[w + 1] = wpfx[w] + __popc(kw[w]);
  }
  // single wave: lane0's writes ordered before subsequent reads
  for (int i = lane; i < 2000; i += 64) {
    if ((kw[i >> 5] >> (i & 31)) & 1u) {
      int r = (int)wpfx[i >> 5] + __popc(kw[i >> 5] & ((1u << (i & 31)) - 1u));
      if (r < 1000) {
        out[OUT_FL + r] = tsc[i];
        out[OUT_FB + r * 4 + 0] = (float)tbox[i * 4 + 0];
        out[OUT_FB + r * 4 + 1] = (float)tbox[i * 4 + 1];
        out[OUT_FB + r * 4 + 2] = (float)tbox[i * 4 + 2];
        out[OUT_FB + r * 4 + 3] = (float)tbox[i * 4 + 3];
      }
    }
  }
}

// ---------------------------------------------------------------- launch
extern "C" void kernel_launch(void* const* d_in, const int* in_sizes, int n_in,
                              void* d_out, int out_size, void* d_ws, size_t ws_size,
                              hipStream_t stream) {
  (void)in_sizes; (void)n_in; (void)out_size; (void)ws_size;
  const float* x      = (const float*)d_in[0];
  const float* conv_w = (const float*)d_in[1];
  const float* conv_b = (const float*)d_in[2];
  const float* gamma  = (const float*)d_in[3];
  const float* beta   = (const float*)d_in[4];
  const float* mean   = (const float*)d_in[5];
  const float* var    = (const float*)d_in[6];
  const float* det_w  = (const float*)d_in[7];
  const float* det_b  = (const float*)d_in[8];
  const float* reg_w  = (const float*)d_in[9];
  const float* reg_b  = (const float*)d_in[10];
  float* out = (float*)d_out;
  char* ws = (char*)d_ws;

  float*  y      = (float*)(ws + Y_OFF);
  double* props  = (double*)(ws + PROPS_OFF);
  float*  wt     = (float*)(ws + PROPS_OFF);   // transient: conv-time only
  float*  keyf   = (float*)(ws + KEYF_OFF);
  unsigned* candk = (unsigned*)(ws + CANDK_OFF);
  unsigned* candi = (unsigned*)(ws + CANDI_OFF);
  float*  tsc    = (float*)(ws + TSC_OFF);
  double* tbox   = (double*)(ws + TBOX_OFF);
  SelState* st   = (SelState*)(ws + STATE_OFF);
  unsigned* mask32 = (unsigned*)(ws + MASK32_OFF);
  float*  wt2    = (float*)(ws + MASK32_OFF);            // transient: heads-time only
  unsigned* h16  = (unsigned*)(ws + MASK32_OFF + 16384); // transient: select-time only

  prep_all<<<2304, 256, 0, stream>>>(conv_w, wt, det_w, reg_w, wt2, out, st);
  conv_hyb_f32r<<<dim3(100, 8), 256, 0, stream>>>(x, wt, conv_b, gamma, beta, mean, var, y);
  heads_kernel<<<400, 64, 0, stream>>>(y, wt2, det_b, reg_b, out, props, keyf, h16);
  hist16_kernel<<<300, 256, 0, stream>>>(keyf, h16);
  pick16_kernel<<<1, 256, 0, stream>>>(h16, st);
  compact_kernel<<<300, 256, 0, stream>>>(keyf, st, candk, candi);
  sort_gather<<<1, 1024, 0, stream>>>(candk, candi, st, props, tsc, tbox);
  iou_mask<<<500, 256, 0, stream>>>(tbox, mask32);
  nms_scan<<<1, 64, 0, stream>>>(mask32, tsc, tbox, out);
}

// Round 13
// 913.448 us; speedup vs baseline: 1.0206x; 1.0206x over previous
//
#include <hip/hip_runtime.h>
#include <math.h>

#define NPIX  25600      // 160*160
#define NANCH 76800      // 3*NPIX

// output layout (float elements)
constexpr int OUT_ANCH = 0;        // 76800*4
constexpr int OUT_OBJ  = 307200;   // 76800
constexpr int OUT_DELT = 384000;   // 76800*4
constexpr int OUT_FL   = 691200;   // 1000
constexpr int OUT_FB   = 692200;   // 1000*4

// workspace layout (bytes)
constexpr size_t Y_OFF      = 0;                        // 26,214,400 (f32)
constexpr size_t PROPS_OFF  = 26214400;                 // 76800*4*8 = 2,457,600
constexpr size_t KEYF_OFF   = PROPS_OFF + 2457600;      // 76800*4
constexpr size_t CANDK_OFF  = KEYF_OFF + 307200;        // 4096*4
constexpr size_t CANDI_OFF  = CANDK_OFF + 16384;        // 4096*4
constexpr size_t TSC_OFF    = CANDI_OFF + 16384;        // 2000*4 -> 8192
constexpr size_t TBOX_OFF   = TSC_OFF + 8192;           // 2000*4*8 -> 65536
constexpr size_t HIST_OFF   = TBOX_OFF + 65536;         // 256*4 -> 1024
constexpr size_t STATE_OFF  = HIST_OFF + 1024;          // -> 256
constexpr size_t MASK32_OFF = STATE_OFF + 256;          // 2000*64*4 = 512000
// NOTE: transposed weights wt[ci][oc][9] (2,359,296 B) live in the PROPS
// region during the conv (props is only written by heads_kernel, after conv).
// wt2[c][16] (16 KB, heads weights) lives at MASK32_OFF during heads:
// iou_mask writes mask32 only AFTER heads completes (stream-ordered).

struct SelState { unsigned prefix; int remaining; int cntHi; int cntEq; };

__device__ __forceinline__ unsigned orderKey32(float f) {
  unsigned u = __float_as_uint(f);
  return (u & 0x80000000u) ? ~u : (u | 0x80000000u);
}
__device__ __forceinline__ float key32ToFloat(unsigned k) {
  unsigned u = (k & 0x80000000u) ? (k & 0x7fffffffu) : ~k;
  return __uint_as_float(u);
}

// ---------------------------------------------------------------- prep_all: init + weight transposes (merged, 1 launch)
// wt[ci][oc][9]  <- conv_w[oc][ci][9]   (72 contiguous floats/ci/wave for conv)
// wt2[c][16]     <- {det_w[0..2][c], reg_w[0..11][c], pad}  (one s_load_dwordx16/c for heads)
__global__ __launch_bounds__(256) void prep_all(const float* __restrict__ w,
                                                float* __restrict__ wt,
                                                const float* __restrict__ det_w,
                                                const float* __restrict__ reg_w,
                                                float* __restrict__ wt2,
                                                float* __restrict__ out,
                                                unsigned* __restrict__ hist,
                                                SelState* __restrict__ st) {
  int gid = blockIdx.x * 256 + threadIdx.x;   // 2304*256 = 589824 exactly
  int oc  = gid / 2304;
  int rem = gid - oc * 2304;
  int ci  = rem / 9;
  int t   = rem - ci * 9;
  wt[((size_t)ci * 256 + oc) * 9 + t] = w[gid];
  if (gid < 4096) {
    int c = gid >> 4, j = gid & 15;
    float v = 0.f;
    if (j < 3) v = det_w[j * 256 + c];
    else if (j < 15) v = reg_w[(j - 3) * 256 + c];
    wt2[gid] = v;
  }
  if (gid < 1000) out[OUT_FL + gid] = -1e9f;
  if (gid < 4000) out[OUT_FB + gid] = 0.f;
  if (gid < 256) hist[gid] = 0u;
  if (gid == 0) { st->prefix = 0u; st->remaining = 2000; st->cntHi = 0; st->cntEq = 0; }
}

// ---------------------------------------------------------------- hybrid conv + bn + relu
// NUMERICS FROZEN (R9/R10/R11 pass): per-output fmaf chain ic 255->0, taps 8->0.
// V5 (proven 566us conv / 930us total): inputs via zero-padded LDS tile;
// weights via SCALAR pipe from transposed wt (L2-resident). V6-V9 all
// regressed (load sinking / wave-ci overhead / SGPR serialization / addressing
// growth) -- this codegen is a verified local optimum; DO NOT perturb.
__global__ __launch_bounds__(256) void conv_hyb_f32r(
    const float* __restrict__ x, const float* __restrict__ wt,
    const float* __restrict__ bv, const float* __restrict__ gamma,
    const float* __restrict__ beta, const float* __restrict__ mean,
    const float* __restrict__ var, float* __restrict__ y) {
  const int tile = blockIdx.x;                 // 100 tiles: 10x10 of 16x16 px
  const int th0 = (tile / 10) * 16;
  const int tw0 = (tile - (tile / 10) * 10) * 16;
  const int ob  = blockIdx.y * 32;             // 32 oc per block
  const int tid = threadIdx.x;
  const int wid  = __builtin_amdgcn_readfirstlane(tid >> 6);   // wave -> 8 oc
  const int lane = tid & 63;
  const int r  = lane >> 2;                    // output row (0..15)
  const int cg = lane & 3;                     // col group (4 px)
  const int oc0 = ob + wid * 8;

  __shared__ __align__(16) float lin[8][18][20];   // 2880 floats; halo 18x18, stride 20

  float sreg[11];                              // 11*256 = 2816 >= 2592 staged elems
  auto loadRegs = [&](int cb) {
#pragma unroll
    for (int k = 0; k < 11; ++k) {
      int idx = tid + k * 256;
      float v = 0.f;
      if (idx < 2592) {
        int ci = idx / 324; int rem = idx - ci * 324;
        int rr = rem / 18;  int cc = rem - rr * 18;
        int gh = th0 + rr - 1, gw = tw0 + cc - 1;
        if ((unsigned)gh < 160u && (unsigned)gw < 160u)
          v = x[(size_t)(cb + ci) * NPIX + gh * 160 + gw];
      }
      sreg[k] = v;
    }
  };
  auto writeRegs = [&]() {
#pragma unroll
    for (int k = 0; k < 11; ++k) {
      int idx = tid + k * 256;
      if (idx < 2592) {
        int ci = idx / 324; int rem = idx - ci * 324;
        int rr = rem / 18;  int cc = rem - rr * 18;
        lin[ci][rr][cc] = sreg[k];
      }
    }
  };

  float acc[8][4];
#pragma unroll
  for (int o = 0; o < 8; ++o)
#pragma unroll
    for (int j = 0; j < 4; ++j) acc[o][j] = 0.f;

  loadRegs(248);
  for (int cb = 248; cb >= 0; cb -= 8) {       // ic blocks DESCENDING
    __syncthreads();
    writeRegs();
    __syncthreads();
    if (cb > 0) loadRegs(cb - 8);              // prefetch next chunk
#pragma unroll
    for (int ci = 7; ci >= 0; --ci) {          // ic DESCENDING within block
      float in0[6], in1[6], in2[6];
      const float* base = &lin[ci][r][cg * 4];     // 16B aligned
      {
        float4 q = *(const float4*)(base);
        float2 p = *(const float2*)(base + 4);
        in0[0] = q.x; in0[1] = q.y; in0[2] = q.z; in0[3] = q.w; in0[4] = p.x; in0[5] = p.y;
      }
      {
        float4 q = *(const float4*)(base + 20);
        float2 p = *(const float2*)(base + 24);
        in1[0] = q.x; in1[1] = q.y; in1[2] = q.z; in1[3] = q.w; in1[4] = p.x; in1[5] = p.y;
      }
      {
        float4 q = *(const float4*)(base + 40);
        float2 p = *(const float2*)(base + 44);
        in2[0] = q.x; in2[1] = q.y; in2[2] = q.z; in2[3] = q.w; in2[4] = p.x; in2[5] = p.y;
      }
      // 72 contiguous floats, wave-uniform address -> wide s_loads (L2-resident)
      const float* wb = wt + ((size_t)(cb + ci) * 256 + oc0) * 9;
#pragma unroll
      for (int o = 0; o < 8; ++o) {
        const float w0 = wb[o * 9 + 0], w1 = wb[o * 9 + 1], w2 = wb[o * 9 + 2];
        const float w3 = wb[o * 9 + 3], w4 = wb[o * 9 + 4], w5 = wb[o * 9 + 5];
        const float w6 = wb[o * 9 + 6], w7 = wb[o * 9 + 7], w8 = wb[o * 9 + 8];
#pragma unroll
        for (int j = 0; j < 4; ++j) {
          // frozen chain: taps 8->0
          float a = acc[o][j];
          a = fmaf(in2[j + 2], w8, a); a = fmaf(in2[j + 1], w7, a); a = fmaf(in2[j + 0], w6, a);
          a = fmaf(in1[j + 2], w5, a); a = fmaf(in1[j + 1], w4, a); a = fmaf(in1[j + 0], w3, a);
          a = fmaf(in0[j + 2], w2, a); a = fmaf(in0[j + 1], w1, a); a = fmaf(in0[j + 0], w0, a);
          acc[o][j] = a;
        }
      }
    }
  }

  const int gh = th0 + r, gw0 = tw0 + cg * 4;
#pragma unroll
  for (int o = 0; o < 8; ++o) {
    int oc = oc0 + o;
    float sc = gamma[oc] / sqrtf(var[oc] + 1e-5f);
    float sh = (bv[oc] - mean[oc]) * sc + beta[oc];
    float4 vv;
    float v0 = fmaf(acc[o][0], sc, sh); vv.x = (v0 > 0.f) ? v0 : 0.f;
    float v1 = fmaf(acc[o][1], sc, sh); vv.y = (v1 > 0.f) ? v1 : 0.f;
    float v2 = fmaf(acc[o][2], sc, sh); vv.z = (v2 > 0.f) ? v2 : 0.f;
    float v3 = fmaf(acc[o][3], sc, sh); vv.w = (v3 > 0.f) ? v3 : 0.f;
    *(float4*)&y[(size_t)oc * NPIX + gh * 160 + gw0] = vv;   // gw0 mult of 4 -> aligned
  }
}

// ---------------------------------------------------------------- heads (f32, reversed c) + anchors + proposals
// NUMERICS FROZEN: identical fmaf chain (c 255->0) with identical weight
// VALUES via packed wt2[c][16] = {det_w[0..2][c], reg_w[0..11][c], pad} ->
// one s_load_dwordx16 per c instead of 15 scattered s_loads. 400x64 blocks
// spread the 25600 threads over all CUs.
__global__ __launch_bounds__(64) void heads_kernel(
    const float* __restrict__ y, const float* __restrict__ wt2,
    const float* __restrict__ det_b, const float* __restrict__ reg_b,
    float* __restrict__ out, double* __restrict__ props,
    float* __restrict__ keyf) {
  const int p = blockIdx.x * 64 + threadIdx.x;
  float od0 = 0.f, od1 = 0.f, od2 = 0.f;
  float rg[12];
#pragma unroll
  for (int o = 0; o < 12; ++o) rg[o] = 0.f;
  const float* yp = y + p;
  for (int c = 255; c >= 0; --c) {      // reversed accumulation
    float v = yp[(size_t)c * NPIX];
    const float* wc = wt2 + c * 16;     // wave-uniform, 64B-aligned -> s_load_dwordx16
    od0 = fmaf(v, wc[0], od0);
    od1 = fmaf(v, wc[1], od1);
    od2 = fmaf(v, wc[2], od2);
#pragma unroll
    for (int o = 0; o < 12; ++o) rg[o] = fmaf(v, wc[3 + o], rg[o]);
  }
  const int hh = p / 160;
  const int ww = p - hh * 160;
  const float sx = ww * 4.0f, sy = hh * 4.0f;
  float odv[3] = {od0, od1, od2};
#pragma unroll
  for (int a = 0; a < 3; ++a) {
    float ar = (a == 0) ? 0.5f : ((a == 1) ? 1.0f : 2.0f);
    float sq = sqrtf(ar);
    float haf = 64.0f * sq, waf = 64.0f / sq;
    float ax1 = fminf(fmaxf(sx - waf * 0.5f, 0.f), 640.f);
    float ay1 = fminf(fmaxf(sy - haf * 0.5f, 0.f), 640.f);
    float ax2 = fminf(fmaxf(sx + waf * 0.5f, 0.f), 640.f);
    float ay2 = fminf(fmaxf(sy + haf * 0.5f, 0.f), 640.f);
    int ai = a * NPIX + p;
    out[OUT_ANCH + ai * 4 + 0] = ax1;
    out[OUT_ANCH + ai * 4 + 1] = ay1;
    out[OUT_ANCH + ai * 4 + 2] = ax2;
    out[OUT_ANCH + ai * 4 + 3] = ay2;
    float logit = odv[a] + det_b[a];
    out[OUT_OBJ + ai] = logit;
    float dx = rg[0 + a] + reg_b[0 + a];
    float dy = rg[3 + a] + reg_b[3 + a];
    float dw = rg[6 + a] + reg_b[6 + a];
    float dh = rg[9 + a] + reg_b[9 + a];
    out[OUT_DELT + ai * 4 + 0] = dx;
    out[OUT_DELT + ai * 4 + 1] = dy;
    out[OUT_DELT + ai * 4 + 2] = dw;
    out[OUT_DELT + ai * 4 + 3] = dh;
    float aw = ax2 - ax1, ah = ay2 - ay1;
    float cx = ax1 + 0.5f * aw, cy = ay1 + 0.5f * ah;
    float pcx = dx * aw + cx, pcy = dy * ah + cy;
    float pw = aw * expf(dw), ph = ah * expf(dh);
    props[ai * 4 + 0] = (double)fminf(fmaxf(pcx - 0.5f * pw, 0.f), 640.f);
    props[ai * 4 + 1] = (double)fminf(fmaxf(pcy - 0.5f * ph, 0.f), 640.f);
    props[ai * 4 + 2] = (double)fminf(fmaxf(pcx + 0.5f * pw, 0.f), 640.f);
    props[ai * 4 + 3] = (double)fminf(fmaxf(pcy + 0.5f * ph, 0.f), 640.f);
    keyf[ai] = (logit > 0.f) ? logit : -1e9f;   // sigmoid>0.5 <=> logit>0
  }
}

// ---------------------------------------------------------------- radix select (R11-proven)
__global__ __launch_bounds__(256) void hist_pass(const float* __restrict__ keyf,
                                                 unsigned* __restrict__ hist,
                                                 const SelState* __restrict__ st, int pass) {
  __shared__ unsigned lh[256];
  lh[threadIdx.x] = 0u;
  __syncthreads();
  unsigned prefix = st->prefix;
  int shift = 24 - 8 * pass;
  int i = blockIdx.x * 256 + threadIdx.x;   // 300*256 = 76800 exactly
  unsigned k = orderKey32(keyf[i]);
  bool ok = (pass == 0) || ((k >> (shift + 8)) == prefix);
  if (ok) atomicAdd(&lh[(k >> shift) & 255u], 1u);
  __syncthreads();
  unsigned c = lh[threadIdx.x];
  if (c) atomicAdd(&hist[threadIdx.x], c);
}

// ---------------------------------------------------------------- pick: wave-parallel (was 1-thread serial scan, ~15us each)
// Selects largest b with suffix(b) >= rem (== first b in descending scan with
// cum + h[b] >= rem); remaining -= suffix(b) - h[b]. Exact original semantics.
__global__ __launch_bounds__(64) void pick_kernel(unsigned* __restrict__ hist,
                                                  SelState* __restrict__ st) {
  const int lane = threadIdx.x;
  const int rem = st->remaining;
  unsigned h0 = hist[lane * 4 + 0], h1 = hist[lane * 4 + 1];
  unsigned h2 = hist[lane * 4 + 2], h3 = hist[lane * 4 + 3];
  unsigned lsum = h0 + h1 + h2 + h3;
  // inclusive suffix-sum across lanes: acc[l] = sum of lsum[l..63]
  unsigned acc = lsum;
#pragma unroll
  for (int off = 1; off < 64; off <<= 1) {
    unsigned other = (unsigned)__shfl_down((int)acc, off);
    if (lane + off < 64) acc += other;
  }
  // highest lane whose bin-range contains a satisfying b: acc (suffix at its
  // lowest bin) is non-increasing in lane -> highest lane with acc >= rem.
  unsigned long long m = __ballot(acc >= (unsigned)rem);
  int L = 63 - __clzll(m);                    // m != 0: total count >= rem by construction
  if (lane == L) {
    unsigned tail = acc - lsum;               // sum over lanes > L
    unsigned s3 = h3 + tail, s2 = h2 + s3, s1 = h1 + s2, s0 = h0 + s1;
    int b; unsigned suf, hsel;
    if (s3 >= (unsigned)rem)      { b = lane * 4 + 3; suf = s3; hsel = h3; }
    else if (s2 >= (unsigned)rem) { b = lane * 4 + 2; suf = s2; hsel = h2; }
    else if (s1 >= (unsigned)rem) { b = lane * 4 + 1; suf = s1; hsel = h1; }
    else                          { b = lane * 4 + 0; suf = s0; hsel = h0; }
    st->prefix = (st->prefix << 8) | (unsigned)b;
    st->remaining = rem - (int)(suf - hsel);
  }
  hist[lane * 4 + 0] = 0u; hist[lane * 4 + 1] = 0u;
  hist[lane * 4 + 2] = 0u; hist[lane * 4 + 3] = 0u;
}

__global__ __launch_bounds__(256) void compact_kernel(const float* __restrict__ keyf,
                                                      SelState* __restrict__ st,
                                                      unsigned* __restrict__ candk,
                                                      unsigned* __restrict__ candi) {
  int i = blockIdx.x * 256 + threadIdx.x;
  if (i >= NANCH) return;
  unsigned k = orderKey32(keyf[i]);
  unsigned T = st->prefix;
  if (k > T) {
    int pos = atomicAdd(&st->cntHi, 1);
    if (pos < 2048) { candk[pos] = k; candi[pos] = (unsigned)i; }
  } else if (k == T) {
    int pos = atomicAdd(&st->cntEq, 1);
    if (pos < 2048) { candk[2048 + pos] = k; candi[2048 + pos] = (unsigned)i; }
  }
}

__global__ __launch_bounds__(1024) void sort_gather(const unsigned* __restrict__ candk,
                                                    const unsigned* __restrict__ candi,
                                                    const SelState* __restrict__ st,
                                                    const double* __restrict__ props,
                                                    float* __restrict__ tsc,
                                                    double* __restrict__ tbox) {
  __shared__ unsigned ka[4096];
  __shared__ unsigned ia[4096];
  int nHi = st->cntHi; if (nHi > 2048) nHi = 2048;
  int nEq = st->cntEq; if (nEq > 2048) nEq = 2048;
  for (int i = threadIdx.x; i < 4096; i += 1024) {
    bool real = (i < nHi) || (i >= 2048 && i < 2048 + nEq);
    ka[i] = real ? candk[i] : 0u;
    ia[i] = real ? candi[i] : 0xffffffffu;
  }
  __syncthreads();
  for (int k = 2; k <= 4096; k <<= 1) {
    for (int j = k >> 1; j > 0; j >>= 1) {
      for (int e = threadIdx.x; e < 4096; e += 1024) {
        int l = e ^ j;
        if (l > e) {
          unsigned ke = ka[e], kl = ka[l];
          unsigned ie = ia[e], il = ia[l];
          bool descending = ((e & k) == 0);
          bool lBetter = (kl > ke) || (kl == ke && il < ie);
          bool eBetter = (ke > kl) || (ke == kl && ie < il);
          bool sw = descending ? lBetter : eBetter;
          if (sw) { ka[e] = kl; ka[l] = ke; ia[e] = il; ia[l] = ie; }
        }
      }
      __syncthreads();
    }
  }
  for (int t = threadIdx.x; t < 2000; t += 1024) {
    unsigned idx = ia[t];
    if (idx < (unsigned)NANCH) {
      tsc[t] = key32ToFloat(ka[t]);
      tbox[t * 4 + 0] = props[(size_t)idx * 4 + 0];
      tbox[t * 4 + 1] = props[(size_t)idx * 4 + 1];
      tbox[t * 4 + 2] = props[(size_t)idx * 4 + 2];
      tbox[t * 4 + 3] = props[(size_t)idx * 4 + 3];
    } else {
      tsc[t] = -1e9f;     // invalid: never kept, never output
      tbox[t * 4 + 0] = 0.0; tbox[t * 4 + 1] = 0.0;
      tbox[t * 4 + 2] = 0.0; tbox[t * 4 + 3] = 0.0;
    }
  }
}

// ---------------------------------------------------------------- IoU bitmask (parallel; f64 formula verbatim from R11 NMS)
// word layout: mask32[i*64 + l] covers j in [l*32, l*32+32); bits only for j>i.
__global__ __launch_bounds__(256) void iou_mask(const double* __restrict__ tbox,
                                                unsigned* __restrict__ mask32) {
  int gid = blockIdx.x * 256 + threadIdx.x;
  if (gid >= 2000 * 64) return;
  int i = gid >> 6, l = gid & 63;
  int j0 = l * 32;
  unsigned m = 0u;
  if (j0 + 31 > i) {                       // word contains some j>i
    double bix = tbox[i * 4 + 0], biy = tbox[i * 4 + 1];
    double biz = tbox[i * 4 + 2], biw = tbox[i * 4 + 3];
    double areai = (biz - bix) * (biw - biy);
#pragma unroll 4
    for (int b = 0; b < 32; ++b) {
      int j = j0 + b;
      if (j >= 2000 || j <= i) continue;
      double bjx = tbox[j * 4 + 0], bjy = tbox[j * 4 + 1];
      double bjz = tbox[j * 4 + 2], bjw = tbox[j * 4 + 3];
      double xx1 = fmax(bix, bjx), yy1 = fmax(biy, bjy);
      double xx2 = fmin(biz, bjz), yy2 = fmin(biw, bjw);
      double iw = fmax(xx2 - xx1, 0.0), ih = fmax(yy2 - yy1, 0.0);
      double inter = iw * ih;
      double areaj = (bjz - bjx) * (bjw - bjy);
      double iou = inter / (areai + areaj - inter + 1e-9);
      if (iou > 0.7) m |= (1u << b);
    }
  }
  mask32[(size_t)i * 64 + l] = m;
}

// ---------------------------------------------------------------- greedy scan V5 (proven): register-resident, word-granular
__global__ __launch_bounds__(64) void nms_scan(const unsigned* __restrict__ mask32,
                                               const float* __restrict__ tsc,
                                               const double* __restrict__ tbox,
                                               float* __restrict__ out) {
  __shared__ unsigned kw[64];
  __shared__ unsigned wpfx[65];
  __shared__ __align__(16) unsigned stage[2][2048];   // 2 x 8KB mask-row slabs
  const int lane = threadIdx.x;

  // valid bits (single wave: LDS ops complete in program order)
  kw[lane] = 0u;
  for (int i = lane; i < 2000; i += 64)
    if (tsc[i] > -5e8f) atomicOr(&kw[i >> 5], 1u << (i & 31));
  const unsigned Vw = kw[lane];      // lane's valid word
  unsigned S = 0u;                   // lane's suppression word (grows monotonically)

  // staging: word w's 32 rows are a CONTIGUOUS 8KB slab mask32[w*2048 .. +2048)
  uint4 s0, s1, s2, s3, s4, s5, s6, s7;
  int nchunks = 0;
  auto stageLoad = [&](int w) {
    int rows = 2000 - w * 32; if (rows > 32) rows = 32;
    nchunks = rows >> 2;                       // 8 full words, 4 for word 62
    const uint4* src = (const uint4*)(mask32 + (size_t)w * 2048);
    if (nchunks > 0) s0 = src[0 * 64 + lane];
    if (nchunks > 1) s1 = src[1 * 64 + lane];
    if (nchunks > 2) s2 = src[2 * 64 + lane];
    if (nchunks > 3) s3 = src[3 * 64 + lane];
    if (nchunks > 4) s4 = src[4 * 64 + lane];
    if (nchunks > 5) s5 = src[5 * 64 + lane];
    if (nchunks > 6) s6 = src[6 * 64 + lane];
    if (nchunks > 7) s7 = src[7 * 64 + lane];
  };
  auto stageWrite = [&](int buf) {
    uint4* dst = (uint4*)&stage[buf][0];
    if (nchunks > 0) dst[0 * 64 + lane] = s0;
    if (nchunks > 1) dst[1 * 64 + lane] = s1;
    if (nchunks > 2) dst[2 * 64 + lane] = s2;
    if (nchunks > 3) dst[3 * 64 + lane] = s3;
    if (nchunks > 4) dst[4 * 64 + lane] = s4;
    if (nchunks > 5) dst[5 * 64 + lane] = s5;
    if (nchunks > 6) dst[6 * 64 + lane] = s6;
    if (nchunks > 7) dst[7 * 64 + lane] = s7;
  };

  stageLoad(0);
  stageWrite(0);                                // word 0 ready (one unavoidable stall)
  for (int w = 0; w < 63; ++w) {                // 63 words cover 2000 candidates
    const int buf = w & 1;
    if (w + 1 < 63) stageLoad(w + 1);           // issue next slab's loads (vmcnt)
    // process word w from stage[buf] (LDS reads hide the in-flight global loads)
    unsigned rem = (unsigned)__shfl((int)(Vw & ~S), w);
    while (rem) {
      int b = __ffs(rem) - 1;                   // lowest set bit = next kept i
      rem &= rem - 1;
      unsigned mlane = stage[buf][b * 64 + lane];   // per-lane mask word of row i
      unsigned supw  = stage[buf][b * 64 + w];      // broadcast: row i's word w
      S |= mlane;                               // suppress in future words
      rem &= ~supw;                             // suppress within current word (bits j>i only)
    }
    if (w + 1 < 63) stageWrite(buf ^ 1);        // write next slab (loads mostly landed)
  }
  kw[lane] = Vw & ~S;                           // final keep words

  if (lane == 0) {
    wpfx[0] = 0;
    for (int w = 0; w < 64; ++w) wpfx[w + 1] = wpfx[w] + __popc(kw[w]);
  }
  // single wave: lane0's writes ordered before subsequent reads
  for (int i = lane; i < 2000; i += 64) {
    if ((kw[i >> 5] >> (i & 31)) & 1u) {
      int r = (int)wpfx[i >> 5] + __popc(kw[i >> 5] & ((1u << (i & 31)) - 1u));
      if (r < 1000) {
        out[OUT_FL + r] = tsc[i];
        out[OUT_FB + r * 4 + 0] = (float)tbox[i * 4 + 0];
        out[OUT_FB + r * 4 + 1] = (float)tbox[i * 4 + 1];
        out[OUT_FB + r * 4 + 2] = (float)tbox[i * 4 + 2];
        out[OUT_FB + r * 4 + 3] = (float)tbox[i * 4 + 3];
      }
    }
  }
}

// ---------------------------------------------------------------- launch
extern "C" void kernel_launch(void* const* d_in, const int* in_sizes, int n_in,
                              void* d_out, int out_size, void* d_ws, size_t ws_size,
                              hipStream_t stream) {
  (void)in_sizes; (void)n_in; (void)out_size; (void)ws_size;
  const float* x      = (const float*)d_in[0];
  const float* conv_w = (const float*)d_in[1];
  const float* conv_b = (const float*)d_in[2];
  const float* gamma  = (const float*)d_in[3];
  const float* beta   = (const float*)d_in[4];
  const float* mean   = (const float*)d_in[5];
  const float* var    = (const float*)d_in[6];
  const float* det_w  = (const float*)d_in[7];
  const float* det_b  = (const float*)d_in[8];
  const float* reg_w  = (const float*)d_in[9];
  const float* reg_b  = (const float*)d_in[10];
  float* out = (float*)d_out;
  char* ws = (char*)d_ws;

  float*  y      = (float*)(ws + Y_OFF);
  double* props  = (double*)(ws + PROPS_OFF);
  float*  wt     = (float*)(ws + PROPS_OFF);   // transient: conv-time only, then heads overwrites with props
  float*  keyf   = (float*)(ws + KEYF_OFF);
  unsigned* candk = (unsigned*)(ws + CANDK_OFF);
  unsigned* candi = (unsigned*)(ws + CANDI_OFF);
  float*  tsc    = (float*)(ws + TSC_OFF);
  double* tbox   = (double*)(ws + TBOX_OFF);
  unsigned* hist = (unsigned*)(ws + HIST_OFF);
  SelState* st   = (SelState*)(ws + STATE_OFF);
  unsigned* mask32 = (unsigned*)(ws + MASK32_OFF);
  float*  wt2    = (float*)(ws + MASK32_OFF);  // transient: heads-time only, then iou_mask overwrites with mask32

  prep_all<<<2304, 256, 0, stream>>>(conv_w, wt, det_w, reg_w, wt2, out, hist, st);
  conv_hyb_f32r<<<dim3(100, 8), 256, 0, stream>>>(x, wt, conv_b, gamma, beta, mean, var, y);
  heads_kernel<<<400, 64, 0, stream>>>(y, wt2, det_b, reg_b, out, props, keyf);
  for (int p = 0; p < 4; ++p) {
    hist_pass<<<300, 256, 0, stream>>>(keyf, hist, st, p);
    pick_kernel<<<1, 64, 0, stream>>>(hist, st);
  }
  compact_kernel<<<300, 256, 0, stream>>>(keyf, st, candk, candi);
  sort_gather<<<1, 1024, 0, stream>>>(candk, candi, st, props, tsc, tbox);
  iou_mask<<<500, 256, 0, stream>>>(tbox, mask32);
  nms_scan<<<1, 64, 0, stream>>>(mask32, tsc, tbox, out);
}

// Round 14
// 909.949 us; speedup vs baseline: 1.0245x; 1.0038x over previous
//
#include <hip/hip_runtime.h>
#include <math.h>

#define NPIX  25600      // 160*160
#define NANCH 76800      // 3*NPIX

// output layout (float elements)
constexpr int OUT_ANCH = 0;        // 76800*4
constexpr int OUT_OBJ  = 307200;   // 76800
constexpr int OUT_DELT = 384000;   // 76800*4
constexpr int OUT_FL   = 691200;   // 1000
constexpr int OUT_FB   = 692200;   // 1000*4

// workspace layout (bytes)
constexpr size_t Y_OFF      = 0;                        // 26,214,400 (f32)
constexpr size_t PROPS_OFF  = 26214400;                 // 76800*4*8 = 2,457,600
constexpr size_t KEYF_OFF   = PROPS_OFF + 2457600;      // 76800*4
constexpr size_t CANDK_OFF  = KEYF_OFF + 307200;        // 4096*4
constexpr size_t CANDI_OFF  = CANDK_OFF + 16384;        // 4096*4
constexpr size_t TSC_OFF    = CANDI_OFF + 16384;        // 2000*4 -> 8192
constexpr size_t TBOX_OFF   = TSC_OFF + 8192;           // 2000*4*8 -> 65536
constexpr size_t HIST_OFF   = TBOX_OFF + 65536;         // 256*4 -> 1024
constexpr size_t STATE_OFF  = HIST_OFF + 1024;          // -> 256
constexpr size_t MASK32_OFF = STATE_OFF + 256;          // 2000*64*4 = 512000
// NOTE: transposed weights wt[ci][oc][9] (2,359,296 B) live in the PROPS
// region during the conv (props is only written by heads_kernel, after conv).
// wt2[c][16] (16 KB, heads weights) lives at MASK32_OFF during heads:
// iou_mask writes mask32 only AFTER heads completes (stream-ordered).

struct SelState { unsigned prefix; int remaining; int cntHi; int cntEq; };

__device__ __forceinline__ unsigned orderKey32(float f) {
  unsigned u = __float_as_uint(f);
  return (u & 0x80000000u) ? ~u : (u | 0x80000000u);
}
__device__ __forceinline__ float key32ToFloat(unsigned k) {
  unsigned u = (k & 0x80000000u) ? (k & 0x7fffffffu) : ~k;
  return __uint_as_float(u);
}

// ---------------------------------------------------------------- prep_all: init + weight transposes (merged, 1 launch)
// wt[ci][oc][9]  <- conv_w[oc][ci][9]   (72 contiguous floats/ci/wave for conv)
// wt2[c][16]     <- {det_w[0..2][c], reg_w[0..11][c], pad}  (one s_load_dwordx16/c for heads)
__global__ __launch_bounds__(256) void prep_all(const float* __restrict__ w,
                                                float* __restrict__ wt,
                                                const float* __restrict__ det_w,
                                                const float* __restrict__ reg_w,
                                                float* __restrict__ wt2,
                                                float* __restrict__ out,
                                                unsigned* __restrict__ hist,
                                                SelState* __restrict__ st) {
  int gid = blockIdx.x * 256 + threadIdx.x;   // 2304*256 = 589824 exactly
  int oc  = gid / 2304;
  int rem = gid - oc * 2304;
  int ci  = rem / 9;
  int t   = rem - ci * 9;
  wt[((size_t)ci * 256 + oc) * 9 + t] = w[gid];
  if (gid < 4096) {
    int c = gid >> 4, j = gid & 15;
    float v = 0.f;
    if (j < 3) v = det_w[j * 256 + c];
    else if (j < 15) v = reg_w[(j - 3) * 256 + c];
    wt2[gid] = v;
  }
  if (gid < 1000) out[OUT_FL + gid] = -1e9f;
  if (gid < 4000) out[OUT_FB + gid] = 0.f;
  if (gid < 256) hist[gid] = 0u;
  if (gid == 0) { st->prefix = 0u; st->remaining = 2000; st->cntHi = 0; st->cntEq = 0; }
}

// ---------------------------------------------------------------- hybrid conv + bn + relu
// NUMERICS FROZEN (R9/R10/R11 pass): per-output fmaf chain ic 255->0, taps 8->0.
// V13 = V5/V11 structure (LDS inputs stride 20 + scalar-pipe weights, proven
// 577us) with ONE single-variable change: lane mapping r=lane&15, cg=lane>>4
// (was r=lane>>2, cg=lane&3). Bank math: b128 base slot = (5r+cg) mod 8; with
// the new mapping every 8-consecutive-lane group hits slots {0,5,2,7,4,1,6,3}
// = all 8 distinct -> conflict-free b128 (old mapping: slot 0 twice, slot 4
// never -> 7.58e7 conflict cycles = ~123us/CU of LDS-pipe serialization).
// Same stride, same LDS bytes, same VGPR, bijective lane<->pixel -> outputs
// bit-identical. (V9's failure was bundling this with stride-36: +LDS +VGPR.)
__global__ __launch_bounds__(256) void conv_hyb_f32r(
    const float* __restrict__ x, const float* __restrict__ wt,
    const float* __restrict__ bv, const float* __restrict__ gamma,
    const float* __restrict__ beta, const float* __restrict__ mean,
    const float* __restrict__ var, float* __restrict__ y) {
  const int tile = blockIdx.x;                 // 100 tiles: 10x10 of 16x16 px
  const int th0 = (tile / 10) * 16;
  const int tw0 = (tile - (tile / 10) * 10) * 16;
  const int ob  = blockIdx.y * 32;             // 32 oc per block
  const int tid = threadIdx.x;
  const int wid  = __builtin_amdgcn_readfirstlane(tid >> 6);   // wave -> 8 oc
  const int lane = tid & 63;
  const int r  = lane & 15;                    // output row (0..15)  [bank-spread mapping]
  const int cg = lane >> 4;                    // col group (4 px)
  const int oc0 = ob + wid * 8;

  __shared__ __align__(16) float lin[8][18][20];   // 2880 floats; halo 18x18, stride 20

  float sreg[11];                              // 11*256 = 2816 >= 2592 staged elems
  auto loadRegs = [&](int cb) {
#pragma unroll
    for (int k = 0; k < 11; ++k) {
      int idx = tid + k * 256;
      float v = 0.f;
      if (idx < 2592) {
        int ci = idx / 324; int rem = idx - ci * 324;
        int rr = rem / 18;  int cc = rem - rr * 18;
        int gh = th0 + rr - 1, gw = tw0 + cc - 1;
        if ((unsigned)gh < 160u && (unsigned)gw < 160u)
          v = x[(size_t)(cb + ci) * NPIX + gh * 160 + gw];
      }
      sreg[k] = v;
    }
  };
  auto writeRegs = [&]() {
#pragma unroll
    for (int k = 0; k < 11; ++k) {
      int idx = tid + k * 256;
      if (idx < 2592) {
        int ci = idx / 324; int rem = idx - ci * 324;
        int rr = rem / 18;  int cc = rem - rr * 18;
        lin[ci][rr][cc] = sreg[k];
      }
    }
  };

  float acc[8][4];
#pragma unroll
  for (int o = 0; o < 8; ++o)
#pragma unroll
    for (int j = 0; j < 4; ++j) acc[o][j] = 0.f;

  loadRegs(248);
  for (int cb = 248; cb >= 0; cb -= 8) {       // ic blocks DESCENDING
    __syncthreads();
    writeRegs();
    __syncthreads();
    if (cb > 0) loadRegs(cb - 8);              // prefetch next chunk
#pragma unroll
    for (int ci = 7; ci >= 0; --ci) {          // ic DESCENDING within block
      float in0[6], in1[6], in2[6];
      const float* base = &lin[ci][r][cg * 4];     // 16B aligned, bank-spread
      {
        float4 q = *(const float4*)(base);
        float2 p = *(const float2*)(base + 4);
        in0[0] = q.x; in0[1] = q.y; in0[2] = q.z; in0[3] = q.w; in0[4] = p.x; in0[5] = p.y;
      }
      {
        float4 q = *(const float4*)(base + 20);
        float2 p = *(const float2*)(base + 24);
        in1[0] = q.x; in1[1] = q.y; in1[2] = q.z; in1[3] = q.w; in1[4] = p.x; in1[5] = p.y;
      }
      {
        float4 q = *(const float4*)(base + 40);
        float2 p = *(const float2*)(base + 44);
        in2[0] = q.x; in2[1] = q.y; in2[2] = q.z; in2[3] = q.w; in2[4] = p.x; in2[5] = p.y;
      }
      // 72 contiguous floats, wave-uniform address -> wide s_loads (L2-resident)
      const float* wb = wt + ((size_t)(cb + ci) * 256 + oc0) * 9;
#pragma unroll
      for (int o = 0; o < 8; ++o) {
        const float w0 = wb[o * 9 + 0], w1 = wb[o * 9 + 1], w2 = wb[o * 9 + 2];
        const float w3 = wb[o * 9 + 3], w4 = wb[o * 9 + 4], w5 = wb[o * 9 + 5];
        const float w6 = wb[o * 9 + 6], w7 = wb[o * 9 + 7], w8 = wb[o * 9 + 8];
#pragma unroll
        for (int j = 0; j < 4; ++j) {
          // frozen chain: taps 8->0
          float a = acc[o][j];
          a = fmaf(in2[j + 2], w8, a); a = fmaf(in2[j + 1], w7, a); a = fmaf(in2[j + 0], w6, a);
          a = fmaf(in1[j + 2], w5, a); a = fmaf(in1[j + 1], w4, a); a = fmaf(in1[j + 0], w3, a);
          a = fmaf(in0[j + 2], w2, a); a = fmaf(in0[j + 1], w1, a); a = fmaf(in0[j + 0], w0, a);
          acc[o][j] = a;
        }
      }
    }
  }

  const int gh = th0 + r, gw0 = tw0 + cg * 4;
#pragma unroll
  for (int o = 0; o < 8; ++o) {
    int oc = oc0 + o;
    float sc = gamma[oc] / sqrtf(var[oc] + 1e-5f);
    float sh = (bv[oc] - mean[oc]) * sc + beta[oc];
    float4 vv;
    float v0 = fmaf(acc[o][0], sc, sh); vv.x = (v0 > 0.f) ? v0 : 0.f;
    float v1 = fmaf(acc[o][1], sc, sh); vv.y = (v1 > 0.f) ? v1 : 0.f;
    float v2 = fmaf(acc[o][2], sc, sh); vv.z = (v2 > 0.f) ? v2 : 0.f;
    float v3 = fmaf(acc[o][3], sc, sh); vv.w = (v3 > 0.f) ? v3 : 0.f;
    *(float4*)&y[(size_t)oc * NPIX + gh * 160 + gw0] = vv;   // gw0 mult of 4 -> aligned
  }
}

// ---------------------------------------------------------------- heads (f32, reversed c) + anchors + proposals
// NUMERICS FROZEN: identical fmaf chain (c 255->0) with identical weight
// VALUES via packed wt2[c][16] = {det_w[0..2][c], reg_w[0..11][c], pad} ->
// one s_load_dwordx16 per c instead of 15 scattered s_loads. 400x64 blocks
// spread the 25600 threads over all CUs.
__global__ __launch_bounds__(64) void heads_kernel(
    const float* __restrict__ y, const float* __restrict__ wt2,
    const float* __restrict__ det_b, const float* __restrict__ reg_b,
    float* __restrict__ out, double* __restrict__ props,
    float* __restrict__ keyf) {
  const int p = blockIdx.x * 64 + threadIdx.x;
  float od0 = 0.f, od1 = 0.f, od2 = 0.f;
  float rg[12];
#pragma unroll
  for (int o = 0; o < 12; ++o) rg[o] = 0.f;
  const float* yp = y + p;
  for (int c = 255; c >= 0; --c) {      // reversed accumulation
    float v = yp[(size_t)c * NPIX];
    const float* wc = wt2 + c * 16;     // wave-uniform, 64B-aligned -> s_load_dwordx16
    od0 = fmaf(v, wc[0], od0);
    od1 = fmaf(v, wc[1], od1);
    od2 = fmaf(v, wc[2], od2);
#pragma unroll
    for (int o = 0; o < 12; ++o) rg[o] = fmaf(v, wc[3 + o], rg[o]);
  }
  const int hh = p / 160;
  const int ww = p - hh * 160;
  const float sx = ww * 4.0f, sy = hh * 4.0f;
  float odv[3] = {od0, od1, od2};
#pragma unroll
  for (int a = 0; a < 3; ++a) {
    float ar = (a == 0) ? 0.5f : ((a == 1) ? 1.0f : 2.0f);
    float sq = sqrtf(ar);
    float haf = 64.0f * sq, waf = 64.0f / sq;
    float ax1 = fminf(fmaxf(sx - waf * 0.5f, 0.f), 640.f);
    float ay1 = fminf(fmaxf(sy - haf * 0.5f, 0.f), 640.f);
    float ax2 = fminf(fmaxf(sx + waf * 0.5f, 0.f), 640.f);
    float ay2 = fminf(fmaxf(sy + haf * 0.5f, 0.f), 640.f);
    int ai = a * NPIX + p;
    out[OUT_ANCH + ai * 4 + 0] = ax1;
    out[OUT_ANCH + ai * 4 + 1] = ay1;
    out[OUT_ANCH + ai * 4 + 2] = ax2;
    out[OUT_ANCH + ai * 4 + 3] = ay2;
    float logit = odv[a] + det_b[a];
    out[OUT_OBJ + ai] = logit;
    float dx = rg[0 + a] + reg_b[0 + a];
    float dy = rg[3 + a] + reg_b[3 + a];
    float dw = rg[6 + a] + reg_b[6 + a];
    float dh = rg[9 + a] + reg_b[9 + a];
    out[OUT_DELT + ai * 4 + 0] = dx;
    out[OUT_DELT + ai * 4 + 1] = dy;
    out[OUT_DELT + ai * 4 + 2] = dw;
    out[OUT_DELT + ai * 4 + 3] = dh;
    float aw = ax2 - ax1, ah = ay2 - ay1;
    float cx = ax1 + 0.5f * aw, cy = ay1 + 0.5f * ah;
    float pcx = dx * aw + cx, pcy = dy * ah + cy;
    float pw = aw * expf(dw), ph = ah * expf(dh);
    props[ai * 4 + 0] = (double)fminf(fmaxf(pcx - 0.5f * pw, 0.f), 640.f);
    props[ai * 4 + 1] = (double)fminf(fmaxf(pcy - 0.5f * ph, 0.f), 640.f);
    props[ai * 4 + 2] = (double)fminf(fmaxf(pcx + 0.5f * pw, 0.f), 640.f);
    props[ai * 4 + 3] = (double)fminf(fmaxf(pcy + 0.5f * ph, 0.f), 640.f);
    keyf[ai] = (logit > 0.f) ? logit : -1e9f;   // sigmoid>0.5 <=> logit>0
  }
}

// ---------------------------------------------------------------- radix select (R11-proven)
__global__ __launch_bounds__(256) void hist_pass(const float* __restrict__ keyf,
                                                 unsigned* __restrict__ hist,
                                                 const SelState* __restrict__ st, int pass) {
  __shared__ unsigned lh[256];
  lh[threadIdx.x] = 0u;
  __syncthreads();
  unsigned prefix = st->prefix;
  int shift = 24 - 8 * pass;
  int i = blockIdx.x * 256 + threadIdx.x;   // 300*256 = 76800 exactly
  unsigned k = orderKey32(keyf[i]);
  bool ok = (pass == 0) || ((k >> (shift + 8)) == prefix);
  if (ok) atomicAdd(&lh[(k >> shift) & 255u], 1u);
  __syncthreads();
  unsigned c = lh[threadIdx.x];
  if (c) atomicAdd(&hist[threadIdx.x], c);
}

// ---------------------------------------------------------------- pick: wave-parallel (was 1-thread serial scan, ~15us each)
// Selects largest b with suffix(b) >= rem (== first b in descending scan with
// cum + h[b] >= rem); remaining -= suffix(b) - h[b]. Exact original semantics.
__global__ __launch_bounds__(64) void pick_kernel(unsigned* __restrict__ hist,
                                                  SelState* __restrict__ st) {
  const int lane = threadIdx.x;
  const int rem = st->remaining;
  unsigned h0 = hist[lane * 4 + 0], h1 = hist[lane * 4 + 1];
  unsigned h2 = hist[lane * 4 + 2], h3 = hist[lane * 4 + 3];
  unsigned lsum = h0 + h1 + h2 + h3;
  // inclusive suffix-sum across lanes: acc[l] = sum of lsum[l..63]
  unsigned acc = lsum;
#pragma unroll
  for (int off = 1; off < 64; off <<= 1) {
    unsigned other = (unsigned)__shfl_down((int)acc, off);
    if (lane + off < 64) acc += other;
  }
  // highest lane whose bin-range contains a satisfying b: acc (suffix at its
  // lowest bin) is non-increasing in lane -> highest lane with acc >= rem.
  unsigned long long m = __ballot(acc >= (unsigned)rem);
  int L = 63 - __clzll(m);                    // m != 0: total count >= rem by construction
  if (lane == L) {
    unsigned tail = acc - lsum;               // sum over lanes > L
    unsigned s3 = h3 + tail, s2 = h2 + s3, s1 = h1 + s2, s0 = h0 + s1;
    int b; unsigned suf, hsel;
    if (s3 >= (unsigned)rem)      { b = lane * 4 + 3; suf = s3; hsel = h3; }
    else if (s2 >= (unsigned)rem) { b = lane * 4 + 2; suf = s2; hsel = h2; }
    else if (s1 >= (unsigned)rem) { b = lane * 4 + 1; suf = s1; hsel = h1; }
    else                          { b = lane * 4 + 0; suf = s0; hsel = h0; }
    st->prefix = (st->prefix << 8) | (unsigned)b;
    st->remaining = rem - (int)(suf - hsel);
  }
  hist[lane * 4 + 0] = 0u; hist[lane * 4 + 1] = 0u;
  hist[lane * 4 + 2] = 0u; hist[lane * 4 + 3] = 0u;
}

__global__ __launch_bounds__(256) void compact_kernel(const float* __restrict__ keyf,
                                                      SelState* __restrict__ st,
                                                      unsigned* __restrict__ candk,
                                                      unsigned* __restrict__ candi) {
  int i = blockIdx.x * 256 + threadIdx.x;
  if (i >= NANCH) return;
  unsigned k = orderKey32(keyf[i]);
  unsigned T = st->prefix;
  if (k > T) {
    int pos = atomicAdd(&st->cntHi, 1);
    if (pos < 2048) { candk[pos] = k; candi[pos] = (unsigned)i; }
  } else if (k == T) {
    int pos = atomicAdd(&st->cntEq, 1);
    if (pos < 2048) { candk[2048 + pos] = k; candi[2048 + pos] = (unsigned)i; }
  }
}

__global__ __launch_bounds__(1024) void sort_gather(const unsigned* __restrict__ candk,
                                                    const unsigned* __restrict__ candi,
                                                    const SelState* __restrict__ st,
                                                    const double* __restrict__ props,
                                                    float* __restrict__ tsc,
                                                    double* __restrict__ tbox) {
  __shared__ unsigned ka[4096];
  __shared__ unsigned ia[4096];
  int nHi = st->cntHi; if (nHi > 2048) nHi = 2048;
  int nEq = st->cntEq; if (nEq > 2048) nEq = 2048;
  for (int i = threadIdx.x; i < 4096; i += 1024) {
    bool real = (i < nHi) || (i >= 2048 && i < 2048 + nEq);
    ka[i] = real ? candk[i] : 0u;
    ia[i] = real ? candi[i] : 0xffffffffu;
  }
  __syncthreads();
  for (int k = 2; k <= 4096; k <<= 1) {
    for (int j = k >> 1; j > 0; j >>= 1) {
      for (int e = threadIdx.x; e < 4096; e += 1024) {
        int l = e ^ j;
        if (l > e) {
          unsigned ke = ka[e], kl = ka[l];
          unsigned ie = ia[e], il = ia[l];
          bool descending = ((e & k) == 0);
          bool lBetter = (kl > ke) || (kl == ke && il < ie);
          bool eBetter = (ke > kl) || (ke == kl && ie < il);
          bool sw = descending ? lBetter : eBetter;
          if (sw) { ka[e] = kl; ka[l] = ke; ia[e] = il; ia[l] = ie; }
        }
      }
      __syncthreads();
    }
  }
  for (int t = threadIdx.x; t < 2000; t += 1024) {
    unsigned idx = ia[t];
    if (idx < (unsigned)NANCH) {
      tsc[t] = key32ToFloat(ka[t]);
      tbox[t * 4 + 0] = props[(size_t)idx * 4 + 0];
      tbox[t * 4 + 1] = props[(size_t)idx * 4 + 1];
      tbox[t * 4 + 2] = props[(size_t)idx * 4 + 2];
      tbox[t * 4 + 3] = props[(size_t)idx * 4 + 3];
    } else {
      tsc[t] = -1e9f;     // invalid: never kept, never output
      tbox[t * 4 + 0] = 0.0; tbox[t * 4 + 1] = 0.0;
      tbox[t * 4 + 2] = 0.0; tbox[t * 4 + 3] = 0.0;
    }
  }
}

// ---------------------------------------------------------------- IoU bitmask (parallel; f64 formula verbatim from R11 NMS)
// word layout: mask32[i*64 + l] covers j in [l*32, l*32+32); bits only for j>i.
__global__ __launch_bounds__(256) void iou_mask(const double* __restrict__ tbox,
                                                unsigned* __restrict__ mask32) {
  int gid = blockIdx.x * 256 + threadIdx.x;
  if (gid >= 2000 * 64) return;
  int i = gid >> 6, l = gid & 63;
  int j0 = l * 32;
  unsigned m = 0u;
  if (j0 + 31 > i) {                       // word contains some j>i
    double bix = tbox[i * 4 + 0], biy = tbox[i * 4 + 1];
    double biz = tbox[i * 4 + 2], biw = tbox[i * 4 + 3];
    double areai = (biz - bix) * (biw - biy);
#pragma unroll 4
    for (int b = 0; b < 32; ++b) {
      int j = j0 + b;
      if (j >= 2000 || j <= i) continue;
      double bjx = tbox[j * 4 + 0], bjy = tbox[j * 4 + 1];
      double bjz = tbox[j * 4 + 2], bjw = tbox[j * 4 + 3];
      double xx1 = fmax(bix, bjx), yy1 = fmax(biy, bjy);
      double xx2 = fmin(biz, bjz), yy2 = fmin(biw, bjw);
      double iw = fmax(xx2 - xx1, 0.0), ih = fmax(yy2 - yy1, 0.0);
      double inter = iw * ih;
      double areaj = (bjz - bjx) * (bjw - bjy);
      double iou = inter / (areai + areaj - inter + 1e-9);
      if (iou > 0.7) m |= (1u << b);
    }
  }
  mask32[(size_t)i * 64 + l] = m;
}

// ---------------------------------------------------------------- greedy scan V5 (proven): register-resident, word-granular
__global__ __launch_bounds__(64) void nms_scan(const unsigned* __restrict__ mask32,
                                               const float* __restrict__ tsc,
                                               const double* __restrict__ tbox,
                                               float* __restrict__ out) {
  __shared__ unsigned kw[64];
  __shared__ unsigned wpfx[65];
  __shared__ __align__(16) unsigned stage[2][2048];   // 2 x 8KB mask-row slabs
  const int lane = threadIdx.x;

  // valid bits (single wave: LDS ops complete in program order)
  kw[lane] = 0u;
  for (int i = lane; i < 2000; i += 64)
    if (tsc[i] > -5e8f) atomicOr(&kw[i >> 5], 1u << (i & 31));
  const unsigned Vw = kw[lane];      // lane's valid word
  unsigned S = 0u;                   // lane's suppression word (grows monotonically)

  // staging: word w's 32 rows are a CONTIGUOUS 8KB slab mask32[w*2048 .. +2048)
  uint4 s0, s1, s2, s3, s4, s5, s6, s7;
  int nchunks = 0;
  auto stageLoad = [&](int w) {
    int rows = 2000 - w * 32; if (rows > 32) rows = 32;
    nchunks = rows >> 2;                       // 8 full words, 4 for word 62
    const uint4* src = (const uint4*)(mask32 + (size_t)w * 2048);
    if (nchunks > 0) s0 = src[0 * 64 + lane];
    if (nchunks > 1) s1 = src[1 * 64 + lane];
    if (nchunks > 2) s2 = src[2 * 64 + lane];
    if (nchunks > 3) s3 = src[3 * 64 + lane];
    if (nchunks > 4) s4 = src[4 * 64 + lane];
    if (nchunks > 5) s5 = src[5 * 64 + lane];
    if (nchunks > 6) s6 = src[6 * 64 + lane];
    if (nchunks > 7) s7 = src[7 * 64 + lane];
  };
  auto stageWrite = [&](int buf) {
    uint4* dst = (uint4*)&stage[buf][0];
    if (nchunks > 0) dst[0 * 64 + lane] = s0;
    if (nchunks > 1) dst[1 * 64 + lane] = s1;
    if (nchunks > 2) dst[2 * 64 + lane] = s2;
    if (nchunks > 3) dst[3 * 64 + lane] = s3;
    if (nchunks > 4) dst[4 * 64 + lane] = s4;
    if (nchunks > 5) dst[5 * 64 + lane] = s5;
    if (nchunks > 6) dst[6 * 64 + lane] = s6;
    if (nchunks > 7) dst[7 * 64 + lane] = s7;
  };

  stageLoad(0);
  stageWrite(0);                                // word 0 ready (one unavoidable stall)
  for (int w = 0; w < 63; ++w) {                // 63 words cover 2000 candidates
    const int buf = w & 1;
    if (w + 1 < 63) stageLoad(w + 1);           // issue next slab's loads (vmcnt)
    // process word w from stage[buf] (LDS reads hide the in-flight global loads)
    unsigned rem = (unsigned)__shfl((int)(Vw & ~S), w);
    while (rem) {
      int b = __ffs(rem) - 1;                   // lowest set bit = next kept i
      rem &= rem - 1;
      unsigned mlane = stage[buf][b * 64 + lane];   // per-lane mask word of row i
      unsigned supw  = stage[buf][b * 64 + w];      // broadcast: row i's word w
      S |= mlane;                               // suppress in future words
      rem &= ~supw;                             // suppress within current word (bits j>i only)
    }
    if (w + 1 < 63) stageWrite(buf ^ 1);        // write next slab (loads mostly landed)
  }
  kw[lane] = Vw & ~S;                           // final keep words

  if (lane == 0) {
    wpfx[0] = 0;
    for (int w = 0; w < 64; ++w) wpfx[w + 1] = wpfx[w] + __popc(kw[w]);
  }
  // single wave: lane0's writes ordered before subsequent reads
  for (int i = lane; i < 2000; i += 64) {
    if ((kw[i >> 5] >> (i & 31)) & 1u) {
      int r = (int)wpfx[i >> 5] + __popc(kw[i >> 5] & ((1u << (i & 31)) - 1u));
      if (r < 1000) {
        out[OUT_FL + r] = tsc[i];
        out[OUT_FB + r * 4 + 0] = (float)tbox[i * 4 + 0];
        out[OUT_FB + r * 4 + 1] = (float)tbox[i * 4 + 1];
        out[OUT_FB + r * 4 + 2] = (float)tbox[i * 4 + 2];
        out[OUT_FB + r * 4 + 3] = (float)tbox[i * 4 + 3];
      }
    }
  }
}

// ---------------------------------------------------------------- launch
extern "C" void kernel_launch(void* const* d_in, const int* in_sizes, int n_in,
                              void* d_out, int out_size, void* d_ws, size_t ws_size,
                              hipStream_t stream) {
  (void)in_sizes; (void)n_in; (void)out_size; (void)ws_size;
  const float* x      = (const float*)d_in[0];
  const float* conv_w = (const float*)d_in[1];
  const float* conv_b = (const float*)d_in[2];
  const float* gamma  = (const float*)d_in[3];
  const float* beta   = (const float*)d_in[4];
  const float* mean   = (const float*)d_in[5];
  const float* var    = (const float*)d_in[6];
  const float* det_w  = (const float*)d_in[7];
  const float* det_b  = (const float*)d_in[8];
  const float* reg_w  = (const float*)d_in[9];
  const float* reg_b  = (const float*)d_in[10];
  float* out = (float*)d_out;
  char* ws = (char*)d_ws;

  float*  y      = (float*)(ws + Y_OFF);
  double* props  = (double*)(ws + PROPS_OFF);
  float*  wt     = (float*)(ws + PROPS_OFF);   // transient: conv-time only, then heads overwrites with props
  float*  keyf   = (float*)(ws + KEYF_OFF);
  unsigned* candk = (unsigned*)(ws + CANDK_OFF);
  unsigned* candi = (unsigned*)(ws + CANDI_OFF);
  float*  tsc    = (float*)(ws + TSC_OFF);
  double* tbox   = (double*)(ws + TBOX_OFF);
  unsigned* hist = (unsigned*)(ws + HIST_OFF);
  SelState* st   = (SelState*)(ws + STATE_OFF);
  unsigned* mask32 = (unsigned*)(ws + MASK32_OFF);
  float*  wt2    = (float*)(ws + MASK32_OFF);  // transient: heads-time only, then iou_mask overwrites with mask32

  prep_all<<<2304, 256, 0, stream>>>(conv_w, wt, det_w, reg_w, wt2, out, hist, st);
  conv_hyb_f32r<<<dim3(100, 8), 256, 0, stream>>>(x, wt, conv_b, gamma, beta, mean, var, y);
  heads_kernel<<<400, 64, 0, stream>>>(y, wt2, det_b, reg_b, out, props, keyf);
  for (int p = 0; p < 4; ++p) {
    hist_pass<<<300, 256, 0, stream>>>(keyf, hist, st, p);
    pick_kernel<<<1, 64, 0, stream>>>(hist, st);
  }
  compact_kernel<<<300, 256, 0, stream>>>(keyf, st, candk, candi);
  sort_gather<<<1, 1024, 0, stream>>>(candk, candi, st, props, tsc, tbox);
  iou_mask<<<500, 256, 0, stream>>>(tbox, mask32);
  nms_scan<<<1, 64, 0, stream>>>(mask32, tsc, tbox, out);
}